// Round 1
// baseline (1230.766 us; speedup 1.0000x reference)
//
#include <hip/hip_runtime.h>

// PointNetConv scatter-max:
//   out[i] = max over edges (src->i) of concat(x[src], pos[src]-pos[i]), 0 if no edges.
// x: [50000,128] f32, pos: [50000,3] f32, edge_index: [2,1600000] int
// out: [50000,131] f32

#define N_NODES 50000
#define N_EDGES 1600000
#define NF      128
#define NOUT    131

// Order-preserving float -> uint mapping (monotone for all finite values):
//   f >= 0 : bits | 0x80000000
//   f <  0 : ~bits
// Mapped 0x00000000 corresponds to NaN -> used as the "empty" sentinel.
__device__ __forceinline__ unsigned mapf(float f) {
    unsigned u = __float_as_uint(f);
    return (u & 0x80000000u) ? ~u : (u | 0x80000000u);
}
__device__ __forceinline__ float unmapf(unsigned u) {
    return (u & 0x80000000u) ? __uint_as_float(u & 0x7fffffffu)
                             : __uint_as_float(~u);
}

// One wave (64 lanes) per edge. Lane l handles x features 2l, 2l+1 (float2 load:
// 64 lanes x 8B = 512B contiguous = the whole x row, perfectly coalesced).
// Lanes 0..2 handle the pos delta.
__global__ void edge_scatter_max(const float* __restrict__ x,
                                 const float* __restrict__ pos,
                                 const int* __restrict__ ei,
                                 unsigned* __restrict__ outu)
{
    const int lane = threadIdx.x & 63;
    const long long wavesPerBlock = blockDim.x >> 6;
    long long gwave = (long long)blockIdx.x * wavesPerBlock + (threadIdx.x >> 6);
    const long long nwaves = (long long)gridDim.x * wavesPerBlock;

    for (long long e = gwave; e < N_EDGES; e += nwaves) {
        const int src = ei[e];
        const int dst = ei[N_EDGES + e];

        const float2 xv = *(const float2*)(&x[(long long)src * NF + lane * 2]);
        unsigned* o = outu + (long long)dst * NOUT;

        atomicMax(&o[lane * 2],     mapf(xv.x));
        atomicMax(&o[lane * 2 + 1], mapf(xv.y));

        if (lane < 3) {
            const float d = pos[src * 3 + lane] - pos[dst * 3 + lane];
            atomicMax(&o[NF + lane], mapf(d));
        }
    }
}

// In-place: uint-mapped -> float, empty segments (sentinel 0) -> 0.0f
__global__ void finalize_kernel(unsigned* __restrict__ buf)
{
    const long long total = (long long)N_NODES * NOUT;
    for (long long i = (long long)blockIdx.x * blockDim.x + threadIdx.x;
         i < total;
         i += (long long)gridDim.x * blockDim.x) {
        const unsigned u = buf[i];
        const float v = (u == 0u) ? 0.0f : unmapf(u);
        ((float*)buf)[i] = v;
    }
}

extern "C" void kernel_launch(void* const* d_in, const int* in_sizes, int n_in,
                              void* d_out, int out_size, void* d_ws, size_t ws_size,
                              hipStream_t stream)
{
    const float* x   = (const float*)d_in[0];
    const float* pos = (const float*)d_in[1];
    const int*   ei  = (const int*)d_in[2];
    unsigned* outu = (unsigned*)d_out;

    // Init output to the mapped "-inf" sentinel (0x00000000). Must happen every
    // call: harness poisons once and never re-poisons between replays.
    hipMemsetAsync(d_out, 0, (size_t)N_NODES * NOUT * sizeof(float), stream);

    // 4 waves per 256-thread block, one wave per edge.
    const int block = 256;
    const int wavesPerBlock = block / 64;
    const int grid = (N_EDGES + wavesPerBlock - 1) / wavesPerBlock;
    edge_scatter_max<<<grid, block, 0, stream>>>(x, pos, ei, outu);

    const long long total = (long long)N_NODES * NOUT;
    const int fgrid = (int)((total + block - 1) / block);
    finalize_kernel<<<fgrid, block, 0, stream>>>(outu);
}

// Round 2
// 375.731 us; speedup vs baseline: 3.2757x; 3.2757x over previous
//
#include <hip/hip_runtime.h>
#include <math.h>

// PointNetConv scatter-max via CSR gather:
//   out[i] = max over edges (src->i) of concat(x[src], pos[src]-pos[i]), 0 if none.
// x: [50000,128] f32, pos: [50000,3] f32, edge_index: [2,1600000] int32
// out: [50000,131] f32
//
// Round-1 lesson (rocprof): per-feature global atomics caused 1.78 GB of HBM
// writeback (WRITE_SIZE) -> 1.2 ms. This version builds CSR by dst and gathers,
// writing each output element exactly once.

#define N_NODES 50000
#define N_EDGES 1600000
#define NF      128
#define NOUT    131

// ---------------- CSR build ----------------

__global__ void hist_kernel(const int* __restrict__ ei, int* __restrict__ counts)
{
    const long long stride = (long long)gridDim.x * blockDim.x;
    for (long long e = (long long)blockIdx.x * blockDim.x + threadIdx.x;
         e < N_EDGES; e += stride) {
        atomicAdd(&counts[ei[N_EDGES + e]], 1);
    }
}

// Single-block exclusive scan of counts[0..N_NODES) -> row_start[] and cursor[].
// cursor may alias counts (per-thread read-before-write of identical indices).
// 1024 threads x 4 elems/thread = 4096/chunk -> 13 chunks.
__global__ void scan_kernel(int* __restrict__ counts_inout,
                            int* __restrict__ row_start)
{
    __shared__ int wsum[16];
    __shared__ int carry_s;
    if (threadIdx.x == 0) carry_s = 0;
    __syncthreads();

    const int lane = threadIdx.x & 63;
    const int wid  = threadIdx.x >> 6;

    for (int base = 0; base < N_NODES; base += 4096) {
        const int idx = base + (int)threadIdx.x * 4;
        int v[4];
        #pragma unroll
        for (int j = 0; j < 4; ++j)
            v[j] = (idx + j < N_NODES) ? counts_inout[idx + j] : 0;
        const int s = v[0] + v[1] + v[2] + v[3];

        // inclusive scan of s across the wave
        int incl = s;
        #pragma unroll
        for (int off = 1; off < 64; off <<= 1) {
            int t = __shfl_up(incl, off, 64);
            if (lane >= off) incl += t;
        }
        if (lane == 63) wsum[wid] = incl;
        __syncthreads();

        const int carry = carry_s;
        int woff = 0;
        for (int w = 0; w < wid; ++w) woff += wsum[w];
        __syncthreads();  // all reads of carry_s/wsum done before updates below

        int excl = carry + woff + incl - s;
        #pragma unroll
        for (int j = 0; j < 4; ++j) {
            if (idx + j < N_NODES) {
                row_start[idx + j]    = excl;
                counts_inout[idx + j] = excl;  // becomes the scatter cursor
            }
            excl += v[j];
        }
        if (threadIdx.x == blockDim.x - 1) carry_s = carry + woff + incl;
        __syncthreads();
    }
    if (threadIdx.x == 0) row_start[N_NODES] = N_EDGES;
}

__global__ void scatter_kernel(const int* __restrict__ ei,
                               int* __restrict__ cursor,
                               int* __restrict__ csr_src)
{
    const long long stride = (long long)gridDim.x * blockDim.x;
    for (long long e = (long long)blockIdx.x * blockDim.x + threadIdx.x;
         e < N_EDGES; e += stride) {
        const int src = ei[e];
        const int dst = ei[N_EDGES + e];
        const int p = atomicAdd(&cursor[dst], 1);
        csr_src[p] = src;
    }
}

// ---------------- gather max ----------------
// One wave per destination node. Lane l reduces features 2l,2l+1 (float2 load:
// the wave reads the whole 512B x-row coalesced). Lanes 0..2 also track pos.
__global__ void gather_max(const float* __restrict__ x,
                           const float* __restrict__ pos,
                           const int* __restrict__ csr_src,
                           const int* __restrict__ row_start,
                           float* __restrict__ out)
{
    const int lane = threadIdx.x & 63;
    const int node = blockIdx.x * (blockDim.x >> 6) + (threadIdx.x >> 6);
    if (node >= N_NODES) return;

    const int beg = row_start[node];
    const int end = row_start[node + 1];

    float2 acc = make_float2(-INFINITY, -INFINITY);
    float pacc = -INFINITY;
    const float pos_i = (lane < 3) ? pos[node * 3 + lane] : 0.f;

    int k = beg;
    // 2x unroll: issue both row loads before the dependent maxes (ILP).
    for (; k + 1 < end; k += 2) {
        const int s0 = csr_src[k];
        const int s1 = csr_src[k + 1];
        const float2 a0 = *(const float2*)(&x[(long long)s0 * NF + lane * 2]);
        const float2 a1 = *(const float2*)(&x[(long long)s1 * NF + lane * 2]);
        float p0 = 0.f, p1 = 0.f;
        if (lane < 3) {
            p0 = pos[s0 * 3 + lane] - pos_i;
            p1 = pos[s1 * 3 + lane] - pos_i;
        }
        acc.x = fmaxf(acc.x, fmaxf(a0.x, a1.x));
        acc.y = fmaxf(acc.y, fmaxf(a0.y, a1.y));
        if (lane < 3) pacc = fmaxf(pacc, fmaxf(p0, p1));
    }
    if (k < end) {
        const int s0 = csr_src[k];
        const float2 a0 = *(const float2*)(&x[(long long)s0 * NF + lane * 2]);
        acc.x = fmaxf(acc.x, a0.x);
        acc.y = fmaxf(acc.y, a0.y);
        if (lane < 3) pacc = fmaxf(pacc, pos[s0 * 3 + lane] - pos_i);
    }

    if (beg == end) { acc.x = 0.f; acc.y = 0.f; pacc = 0.f; }  // PyG zero-fill

    float* orow = out + (long long)node * NOUT;
    // rows are 524B -> odd rows only 4B-aligned: scalar stores.
    orow[lane * 2]     = acc.x;
    orow[lane * 2 + 1] = acc.y;
    if (lane < 3) orow[NF + lane] = pacc;
}

// ---------------- round-1 fallback (atomic path) if ws is too small ----------

__device__ __forceinline__ unsigned mapf(float f) {
    unsigned u = __float_as_uint(f);
    return (u & 0x80000000u) ? ~u : (u | 0x80000000u);
}
__device__ __forceinline__ float unmapf(unsigned u) {
    return (u & 0x80000000u) ? __uint_as_float(u & 0x7fffffffu)
                             : __uint_as_float(~u);
}

__global__ void edge_scatter_max(const float* __restrict__ x,
                                 const float* __restrict__ pos,
                                 const int* __restrict__ ei,
                                 unsigned* __restrict__ outu)
{
    const int lane = threadIdx.x & 63;
    const long long wavesPerBlock = blockDim.x >> 6;
    long long gwave = (long long)blockIdx.x * wavesPerBlock + (threadIdx.x >> 6);
    const long long nwaves = (long long)gridDim.x * wavesPerBlock;
    for (long long e = gwave; e < N_EDGES; e += nwaves) {
        const int src = ei[e];
        const int dst = ei[N_EDGES + e];
        const float2 xv = *(const float2*)(&x[(long long)src * NF + lane * 2]);
        unsigned* o = outu + (long long)dst * NOUT;
        atomicMax(&o[lane * 2],     mapf(xv.x));
        atomicMax(&o[lane * 2 + 1], mapf(xv.y));
        if (lane < 3) {
            const float d = pos[src * 3 + lane] - pos[dst * 3 + lane];
            atomicMax(&o[NF + lane], mapf(d));
        }
    }
}

__global__ void finalize_kernel(unsigned* __restrict__ buf)
{
    const long long total = (long long)N_NODES * NOUT;
    for (long long i = (long long)blockIdx.x * blockDim.x + threadIdx.x;
         i < total; i += (long long)gridDim.x * blockDim.x) {
        const unsigned u = buf[i];
        ((float*)buf)[i] = (u == 0u) ? 0.0f : unmapf(u);
    }
}

// ---------------- launch ----------------

extern "C" void kernel_launch(void* const* d_in, const int* in_sizes, int n_in,
                              void* d_out, int out_size, void* d_ws, size_t ws_size,
                              hipStream_t stream)
{
    const float* x   = (const float*)d_in[0];
    const float* pos = (const float*)d_in[1];
    const int*   ei  = (const int*)d_in[2];
    float* out = (float*)d_out;

    // ws layout: cursor/counts [50000], row_start [50001] (aligned), csr_src [1.6M]
    const size_t cursor_off = 0;
    const size_t rowst_off  = ((size_t)N_NODES * 4 + 255) & ~(size_t)255;
    const size_t csr_off    = (rowst_off + ((size_t)(N_NODES + 1) * 4) + 255) & ~(size_t)255;
    const size_t ws_needed  = csr_off + (size_t)N_EDGES * 4;

    if (ws_size < ws_needed) {
        // fallback: round-1 atomic path
        unsigned* outu = (unsigned*)d_out;
        hipMemsetAsync(d_out, 0, (size_t)N_NODES * NOUT * sizeof(float), stream);
        const int block = 256;
        const int grid = (N_EDGES + 3) / 4;
        edge_scatter_max<<<grid, block, 0, stream>>>(x, pos, ei, outu);
        const long long total = (long long)N_NODES * NOUT;
        finalize_kernel<<<(int)((total + 255) / 256), 256, 0, stream>>>(outu);
        return;
    }

    int* cursor    = (int*)((char*)d_ws + cursor_off);
    int* row_start = (int*)((char*)d_ws + rowst_off);
    int* csr_src   = (int*)((char*)d_ws + csr_off);

    hipMemsetAsync(cursor, 0, (size_t)N_NODES * 4, stream);

    hist_kernel<<<2048, 256, 0, stream>>>(ei, cursor);
    scan_kernel<<<1, 1024, 0, stream>>>(cursor, row_start);
    scatter_kernel<<<2048, 256, 0, stream>>>(ei, cursor, csr_src);

    // one wave per node, 4 waves per block
    const int gblock = 256;
    const int gwpb = gblock / 64;
    const int ggrid = (N_NODES + gwpb - 1) / gwpb;
    gather_max<<<ggrid, gblock, 0, stream>>>(x, pos, csr_src, row_start, out);
}